// Round 1
// baseline (410.885 us; speedup 1.0000x reference)
//
#include <hip/hip_runtime.h>
#include <stdint.h>

// BitLinear: out[t,o] = (sum_i clip(rint(x/xs)) * clip(rint(w/ws))) * xs*ws
// M=8192, N=4096, K=4096.
// R3: 256x256 tile, 8-wave, 4-phase counted-vmcnt schedule (T3+T4+T5 port of the
// verified bf16 8-phase template to i8 32x32x32 MFMA).
//   - BK=128 bytes, LDS = A[2][256][128] + B[2][256][128] = 128 KiB (double buffer)
//   - stage granularity: 64-row "quarter" = one global_load_lds across 512 threads
//     (8 KB); 8 quarters per K-tile, 2 staged per phase, ALWAYS into the non-current
//     buffer (no same-buffer WAR hazards; barriers make read-drain precede overwrite)
//   - per-wave vmcnt ledger (1 vmem instr per stage call per wave):
//       enter tile t: 2 in flight {S(t,Aq1),S(t,Aq3)}
//       ph0 +2 {S(t+1,Aq0),S(t+1,Aq2)} -> 4
//       ph1 +2 {S(t+1,Bq0),S(t+1,Bq1)} -> 6 ; vmcnt(4) retires S(t,Aq1/Aq3)  [ph2 reads them]
//       ph2 +2 {S(t+1,Bq2),S(t+1,Bq3)} -> 6
//       ph3 +2 {S(t+1,Aq1),S(t+1,Aq3)} -> 8 ; vmcnt(2) retires t+1's early-six [ph0 reads them]
//     -> never vmcnt(0) in the main loop; every load has >=2 phases of hiding.
//   - XOR-swizzled LDS rows (chunk ^= row&7) kept: ds_read_b128 frags conflict-free;
//     global_load_lds keeps linear LDS dest, source chunk pre-swizzled per lane.
//   - raw s_barrier (no vmcnt(0) drain); ds_reads are plain C++ so the compiler
//     tracks deps and emits fine lgkmcnt itself (no inline-asm-ds hazard).
//   - XCD-aware bijective swizzle, column-grouped (2 B-panels per XCD stay L2-hot).

typedef int  int4v  __attribute__((ext_vector_type(4)));
typedef int  int16v __attribute__((ext_vector_type(16)));

typedef __attribute__((address_space(1))) void gvoid;
typedef __attribute__((address_space(3))) void lvoid;

#define M_DIM 8192
#define N_DIM 4096
#define K_DIM 4096

#define BM 256
#define BN 256
#define BK 128          // K-bytes per tile
#define NT (K_DIM / BK) // 32 K-tiles

// ---------------- quantize: fp32 -> int8 ----------------
__global__ __launch_bounds__(256) void quant_kernel(
    const float* __restrict__ in, int8_t* __restrict__ out,
    const float* __restrict__ scale_ptr, float lo, float hi, long n) {
  long i = ((long)blockIdx.x * blockDim.x + threadIdx.x) * 16;
  if (i >= n) return;
  float s = scale_ptr[0];
  float4 a = *(const float4*)(in + i);
  float4 b = *(const float4*)(in + i + 4);
  float4 c = *(const float4*)(in + i + 8);
  float4 d = *(const float4*)(in + i + 12);
  float v[16] = {a.x, a.y, a.z, a.w, b.x, b.y, b.z, b.w,
                 c.x, c.y, c.z, c.w, d.x, d.y, d.z, d.w};
  union { int8_t c[16]; int4 q; } u;
#pragma unroll
  for (int t = 0; t < 16; ++t) {
    float q = rintf(v[t] / s);           // round-half-even, matches np.round
    q = fminf(fmaxf(q, lo), hi);
    u.c[t] = (int8_t)q;
  }
  *(int4*)(out + i) = u.q;
}

// ---------------- GEMM: C[M,N] = A[M,K] * B[N,K]^T (i8 -> i32), scaled ----------------
__global__ __launch_bounds__(512, 2) void gemm_bt(
    const int8_t* __restrict__ A,   // [M,K] i8 (x_q)
    const int8_t* __restrict__ B,   // [N,K] i8 (w_q)
    float* __restrict__ C,          // [M,N]
    const float* __restrict__ ws_ptr, const float* __restrict__ xs_ptr) {
  // LDS: A buffers [2][256][128] at 0; B buffers [2][256][128] at 65536.
  __shared__ __attribute__((aligned(16))) char smem[131072];

  const int tid  = threadIdx.x;
  const int wid  = tid >> 6;      // 0..7
  const int lane = tid & 63;
  const int wr   = wid >> 2;      // 0..1 -> 128-row strip of C
  const int wc   = wid & 3;       // 0..3 -> 64-col strip of C
  const int r    = lane & 31;     // MFMA row/col within 32-tile
  const int half = lane >> 5;     // k-half of fragment

  // XCD swizzle: 512 blocks, 8 XCDs -> each XCD gets 64 consecutive virtual ids,
  // column-grouped (vbx = vid/32): 2 B-panels (2 MB) stay hot in that XCD's L2.
  const int fl  = blockIdx.y * gridDim.x + blockIdx.x;   // 0..511, x-fastest HW order
  const int vid = (fl & 7) * 64 + (fl >> 3);             // bijective (512 % 8 == 0)
  const long m0 = (long)(vid & 31) * BM;
  const long n0 = (long)(vid >> 5) * BN;

  // ---- staging addressing ----
  // One stage call = 512 threads x 16B = 8 KB = 64 rows ("quarter").
  // wave w covers rows q*64 + w*8 + (lane>>3); LDS dest is linear (base + lane*16);
  // source chunk pre-swizzled: (lane&7) ^ (row&7), row&7 == lane>>3 here.
  const int srow   = wid * 8 + (lane >> 3);
  const int schunk = ((lane & 7) ^ (lane >> 3)) * 16;
  const int8_t* gA = A + (m0 + srow) * K_DIM + schunk;
  const int8_t* gB = B + (n0 + srow) * K_DIM + schunk;
  const int ldst = wid * 1024;   // wave's LDS offset within a quarter (HW adds lane*16)

  // ---- fragment read offsets (bytes) ----
  // frag (row, kstep ks): byte = row*128 + (((ks*2+half) ^ (row&7)) * 16); row&7 == r&7.
  int aRow[4], bRow[2], co[4];
#pragma unroll
  for (int m = 0; m < 4; ++m) aRow[m] = (wr * 128 + m * 32 + r) * BK;
#pragma unroll
  for (int n = 0; n < 2; ++n) bRow[n] = (wc * 64 + n * 32 + r) * BK;
#pragma unroll
  for (int ks = 0; ks < 4; ++ks) co[ks] = ((ks * 2 + half) ^ (r & 7)) * 16;

#define STAGE_A(kk, q, nb)                                                         \
  __builtin_amdgcn_global_load_lds(                                                \
      (gvoid*)(gA + (long)(kk) * BK + (long)(q) * 64 * K_DIM),                     \
      (lvoid*)(smem + (nb) * 32768 + (q) * 8192 + ldst), 16, 0, 0)
#define STAGE_B(kk, q, nb)                                                         \
  __builtin_amdgcn_global_load_lds(                                                \
      (gvoid*)(gB + (long)(kk) * BK + (long)(q) * 64 * K_DIM),                     \
      (lvoid*)(smem + 65536 + (nb) * 32768 + (q) * 8192 + ldst), 16, 0, 0)

  // ---- prologue: tile 0 -> buf 0. Early-six (Aq0,Aq2,Bq0..3), late-two (Aq1,Aq3).
  STAGE_A(0, 0, 0); STAGE_A(0, 2, 0);
  STAGE_B(0, 0, 0); STAGE_B(0, 1, 0); STAGE_B(0, 2, 0); STAGE_B(0, 3, 0);
  STAGE_A(0, 1, 0); STAGE_A(0, 3, 0);
  asm volatile("s_waitcnt vmcnt(2)" ::: "memory");  // early-six landed; 2 in flight
  __builtin_amdgcn_s_barrier();

  int4v  a[2][4], b0[4], b1[4];
  int16v acc[4][2] = {};

#pragma unroll 2
  for (int t = 0; t < NT; ++t) {
    const int bi = t & 1;
    const int nb = bi ^ 1;
    const char* sAb = smem + bi * 32768;
    const char* sBb = smem + 65536 + bi * 32768;
    int kk = t + 1; if (kk >= NT) kk = NT - 1;  // last iter re-stages tile 31 (unread, in-bounds)

    // -------- phase 0: reads A-mh0 + B-n0 | stage A q0,q2 | MFMA (m0,m1) x n0 --------
#pragma unroll
    for (int m = 0; m < 2; ++m)
#pragma unroll
      for (int ks = 0; ks < 4; ++ks)
        a[m][ks] = *(const int4v*)(sAb + aRow[m] + co[ks]);
#pragma unroll
    for (int ks = 0; ks < 4; ++ks)
      b0[ks] = *(const int4v*)(sBb + bRow[0] + co[ks]);
    STAGE_A(kk, 0, nb); STAGE_A(kk, 2, nb);
    __builtin_amdgcn_s_barrier();
    __builtin_amdgcn_s_setprio(1);
#pragma unroll
    for (int ks = 0; ks < 4; ++ks) {
      acc[0][0] = __builtin_amdgcn_mfma_i32_32x32x32_i8(a[0][ks], b0[ks], acc[0][0], 0, 0, 0);
      acc[1][0] = __builtin_amdgcn_mfma_i32_32x32x32_i8(a[1][ks], b0[ks], acc[1][0], 0, 0, 0);
    }
    __builtin_amdgcn_s_setprio(0);
    __builtin_amdgcn_s_barrier();

    // -------- phase 1: reads B-n1 | stage B q0,q1 | vmcnt(4) | MFMA (m0,m1) x n1 --------
#pragma unroll
    for (int ks = 0; ks < 4; ++ks)
      b1[ks] = *(const int4v*)(sBb + bRow[1] + co[ks]);
    STAGE_B(kk, 0, nb); STAGE_B(kk, 1, nb);
    asm volatile("s_waitcnt vmcnt(4)" ::: "memory");  // retires S(t,Aq1),S(t,Aq3)
    __builtin_amdgcn_s_barrier();
    __builtin_amdgcn_s_setprio(1);
#pragma unroll
    for (int ks = 0; ks < 4; ++ks) {
      acc[0][1] = __builtin_amdgcn_mfma_i32_32x32x32_i8(a[0][ks], b1[ks], acc[0][1], 0, 0, 0);
      acc[1][1] = __builtin_amdgcn_mfma_i32_32x32x32_i8(a[1][ks], b1[ks], acc[1][1], 0, 0, 0);
    }
    __builtin_amdgcn_s_setprio(0);
    __builtin_amdgcn_s_barrier();

    // -------- phase 2: reads A-mh1 | stage B q2,q3 | MFMA (m2,m3) x n1 --------
#pragma unroll
    for (int m = 0; m < 2; ++m)
#pragma unroll
      for (int ks = 0; ks < 4; ++ks)
        a[m][ks] = *(const int4v*)(sAb + aRow[2 + m] + co[ks]);
    STAGE_B(kk, 2, nb); STAGE_B(kk, 3, nb);
    __builtin_amdgcn_s_barrier();
    __builtin_amdgcn_s_setprio(1);
#pragma unroll
    for (int ks = 0; ks < 4; ++ks) {
      acc[2][1] = __builtin_amdgcn_mfma_i32_32x32x32_i8(a[0][ks], b1[ks], acc[2][1], 0, 0, 0);
      acc[3][1] = __builtin_amdgcn_mfma_i32_32x32x32_i8(a[1][ks], b1[ks], acc[3][1], 0, 0, 0);
    }
    __builtin_amdgcn_s_setprio(0);
    __builtin_amdgcn_s_barrier();

    // -------- phase 3: stage A q1,q3 | vmcnt(2) | MFMA (m2,m3) x n0 --------
    STAGE_A(kk, 1, nb); STAGE_A(kk, 3, nb);
    asm volatile("s_waitcnt vmcnt(2)" ::: "memory");  // retires t+1's early-six
    __builtin_amdgcn_s_barrier();
    __builtin_amdgcn_s_setprio(1);
#pragma unroll
    for (int ks = 0; ks < 4; ++ks) {
      acc[2][0] = __builtin_amdgcn_mfma_i32_32x32x32_i8(a[0][ks], b0[ks], acc[2][0], 0, 0, 0);
      acc[3][0] = __builtin_amdgcn_mfma_i32_32x32x32_i8(a[1][ks], b0[ks], acc[3][0], 0, 0, 0);
    }
    __builtin_amdgcn_s_setprio(0);
    __builtin_amdgcn_s_barrier();
  }
  asm volatile("s_waitcnt vmcnt(0)" ::: "memory");  // drain tail stages before epilogue

  // epilogue: 32x32 C/D layout col=lane&31, row=(reg&3)+8*(reg>>2)+4*(lane>>5)
  const float s = ws_ptr[0] * xs_ptr[0];
#pragma unroll
  for (int m = 0; m < 4; ++m) {
#pragma unroll
    for (int n = 0; n < 2; ++n) {
      const long col = n0 + wc * 64 + n * 32 + r;
      const long rowbase = m0 + wr * 128 + m * 32 + 4 * half;
#pragma unroll
      for (int reg = 0; reg < 16; ++reg) {
        const long row = rowbase + (reg & 3) + 8 * (reg >> 2);
        C[row * N_DIM + col] = (float)acc[m][n][reg] * s;
      }
    }
  }
#undef STAGE_A
#undef STAGE_B
}

extern "C" void kernel_launch(void* const* d_in, const int* in_sizes, int n_in,
                              void* d_out, int out_size, void* d_ws, size_t ws_size,
                              hipStream_t stream) {
  const float* x  = (const float*)d_in[0];   // [8192,4096]
  const float* w  = (const float*)d_in[1];   // [4096,4096]
  const float* ws = (const float*)d_in[2];   // [1]
  const float* xs = (const float*)d_in[3];   // [1]
  float* out = (float*)d_out;

  int8_t* xq = (int8_t*)d_ws;
  int8_t* wq = (int8_t*)d_ws + (size_t)M_DIM * K_DIM;

  const long n_x = (long)M_DIM * K_DIM;
  const long n_w = (long)N_DIM * K_DIM;

  quant_kernel<<<(n_x / 16 + 255) / 256, 256, 0, stream>>>(x, xq, xs, -128.f, 127.f, n_x);
  quant_kernel<<<(n_w / 16 + 255) / 256, 256, 0, stream>>>(w, wq, ws, -1.f, 1.f, n_w);

  dim3 grid(N_DIM / BN, M_DIM / BM);   // 16 x 32 = 512 blocks, 2 full waves over 256 CUs
  gemm_bt<<<grid, 512, 0, stream>>>(xq, wq, out, ws, xs);
}

// Round 2
// 402.819 us; speedup vs baseline: 1.0200x; 1.0200x over previous
//
#include <hip/hip_runtime.h>
#include <stdint.h>

// BitLinear: out[t,o] = (sum_i clip(rint(x/xs)) * clip(rint(w/ws))) * xs*ws
// M=8192, N=4096, K=4096.
// R4: (1) quant kernels rewritten fully-coalesced (the R3 profile showed they cost
//     ~245 us combined: 64B-strided float4 loads thrashed L1). Now one fused kernel,
//     contiguous per-instruction float4 loads + int (4x int8) stores.
//     (2) gemm: drop the post-MFMA barrier of each phase (8 -> 4 barriers/tile).
//     Safety: stages always write the non-current buffer; every cross-tile LDS
//     hazard is ordered by {pre-MFMA barrier + counted-vmcnt asm (memory clobber) +
//     compiler lgkmcnt before MFMA reg use}. Ledger unchanged:
//       enter tile t: 2 in flight {S(t,Aq1),S(t,Aq3)}
//       ph0 +2 {S(t+1,Aq0),S(t+1,Aq2)} -> 4
//       ph1 +2 {S(t+1,Bq0),S(t+1,Bq1)} -> 6 ; vmcnt(4) retires S(t,Aq1/Aq3) [ph2 reads]
//       ph2 +2 {S(t+1,Bq2),S(t+1,Bq3)} -> 6
//       ph3 +2 {S(t+1,Aq1),S(t+1,Aq3)} -> 8 ; vmcnt(2) retires t+1's early-six [ph0 reads]
//     never vmcnt(0) in the main loop.

typedef int  int4v  __attribute__((ext_vector_type(4)));
typedef int  int16v __attribute__((ext_vector_type(16)));

typedef __attribute__((address_space(1))) void gvoid;
typedef __attribute__((address_space(3))) void lvoid;

#define M_DIM 8192
#define N_DIM 4096
#define K_DIM 4096

#define BM 256
#define BN 256
#define BK 128          // K-bytes per tile
#define NT (K_DIM / BK) // 32 K-tiles

// ---------------- quantize: fp32 -> int8 (fused, fully coalesced) ----------------
// Each block handles 2048 consecutive elements: 2 passes of (256 threads x float4).
// Loads: 16B/lane contiguous. Stores: 4B/lane contiguous. Branches are block-uniform.
__global__ __launch_bounds__(256) void quant_fused(
    const float* __restrict__ x, int8_t* __restrict__ xq,
    const float* __restrict__ w, int8_t* __restrict__ wq,
    const float* __restrict__ xs_ptr, const float* __restrict__ ws_ptr,
    int nx_blocks) {
  const bool isX = ((int)blockIdx.x < nx_blocks);
  const float* __restrict__ in  = isX ? x : w;
  int8_t* __restrict__ out      = isX ? xq : wq;
  const float s  = isX ? xs_ptr[0] : ws_ptr[0];
  const float lo = isX ? -128.f : -1.f;
  const float hi = isX ?  127.f :  1.f;
  const long base = (long)(isX ? blockIdx.x : (blockIdx.x - nx_blocks)) * 2048;
#pragma unroll
  for (int p = 0; p < 2; ++p) {
    const long i = base + (long)p * 1024 + (long)threadIdx.x * 4;
    float4 v = *(const float4*)(in + i);
    float e[4] = {v.x, v.y, v.z, v.w};
    union { int8_t c[4]; int u; } u;
#pragma unroll
    for (int t = 0; t < 4; ++t) {
      float q = rintf(e[t] / s);          // round-half-even, matches np.round
      q = fminf(fmaxf(q, lo), hi);
      u.c[t] = (int8_t)q;
    }
    *(int*)(out + i) = u.u;
  }
}

// ---------------- GEMM: C[M,N] = A[M,K] * B[N,K]^T (i8 -> i32), scaled ----------------
__global__ __launch_bounds__(512, 2) void gemm_bt(
    const int8_t* __restrict__ A,   // [M,K] i8 (x_q)
    const int8_t* __restrict__ B,   // [N,K] i8 (w_q)
    float* __restrict__ C,          // [M,N]
    const float* __restrict__ ws_ptr, const float* __restrict__ xs_ptr) {
  // LDS: A buffers [2][256][128] at 0; B buffers [2][256][128] at 65536.
  __shared__ __attribute__((aligned(16))) char smem[131072];

  const int tid  = threadIdx.x;
  const int wid  = tid >> 6;      // 0..7
  const int lane = tid & 63;
  const int wr   = wid >> 2;      // 0..1 -> 128-row strip of C
  const int wc   = wid & 3;       // 0..3 -> 64-col strip of C
  const int r    = lane & 31;     // MFMA row/col within 32-tile
  const int half = lane >> 5;     // k-half of fragment

  // XCD swizzle: 512 blocks, 8 XCDs -> each XCD gets 64 consecutive virtual ids,
  // column-grouped: 2 B-panels stay hot in that XCD's L2.
  const int fl  = blockIdx.y * gridDim.x + blockIdx.x;   // 0..511, x-fastest HW order
  const int vid = (fl & 7) * 64 + (fl >> 3);             // bijective (512 % 8 == 0)
  const long m0 = (long)(vid & 31) * BM;
  const long n0 = (long)(vid >> 5) * BN;

  // ---- staging addressing ----
  // One stage call = 512 threads x 16B = 8 KB = 64 rows ("quarter").
  // LDS dest linear (base + lane*16); source chunk pre-swizzled: (lane&7)^(row&7).
  const int srow   = wid * 8 + (lane >> 3);
  const int schunk = ((lane & 7) ^ (lane >> 3)) * 16;
  const int8_t* gA = A + (m0 + srow) * K_DIM + schunk;
  const int8_t* gB = B + (n0 + srow) * K_DIM + schunk;
  const int ldst = wid * 1024;   // wave's LDS offset within a quarter (HW adds lane*16)

  // ---- fragment read offsets (bytes) ----
  // frag (row, kstep ks): byte = row*128 + (((ks*2+half) ^ (row&7)) * 16); row&7 == r&7.
  int aRow[4], bRow[2], co[4];
#pragma unroll
  for (int m = 0; m < 4; ++m) aRow[m] = (wr * 128 + m * 32 + r) * BK;
#pragma unroll
  for (int n = 0; n < 2; ++n) bRow[n] = (wc * 64 + n * 32 + r) * BK;
#pragma unroll
  for (int ks = 0; ks < 4; ++ks) co[ks] = ((ks * 2 + half) ^ (r & 7)) * 16;

#define STAGE_A(kk, q, nb)                                                         \
  __builtin_amdgcn_global_load_lds(                                                \
      (gvoid*)(gA + (long)(kk) * BK + (long)(q) * 64 * K_DIM),                     \
      (lvoid*)(smem + (nb) * 32768 + (q) * 8192 + ldst), 16, 0, 0)
#define STAGE_B(kk, q, nb)                                                         \
  __builtin_amdgcn_global_load_lds(                                                \
      (gvoid*)(gB + (long)(kk) * BK + (long)(q) * 64 * K_DIM),                     \
      (lvoid*)(smem + 65536 + (nb) * 32768 + (q) * 8192 + ldst), 16, 0, 0)

  // ---- prologue: tile 0 -> buf 0. Early-six (Aq0,Aq2,Bq0..3), late-two (Aq1,Aq3).
  STAGE_A(0, 0, 0); STAGE_A(0, 2, 0);
  STAGE_B(0, 0, 0); STAGE_B(0, 1, 0); STAGE_B(0, 2, 0); STAGE_B(0, 3, 0);
  STAGE_A(0, 1, 0); STAGE_A(0, 3, 0);
  asm volatile("s_waitcnt vmcnt(2)" ::: "memory");  // early-six landed; 2 in flight
  __builtin_amdgcn_s_barrier();

  int4v  a[2][4], b0[4], b1[4];
  int16v acc[4][2] = {};

#pragma unroll 2
  for (int t = 0; t < NT; ++t) {
    const int bi = t & 1;
    const int nb = bi ^ 1;
    const char* sAb = smem + bi * 32768;
    const char* sBb = smem + 65536 + bi * 32768;
    int kk = t + 1; if (kk >= NT) kk = NT - 1;  // last iter re-stages tile 31 (unread, in-bounds)

    // -------- phase 0: reads A-mh0 + B-n0 | stage A q0,q2 | MFMA (m0,m1) x n0 --------
#pragma unroll
    for (int m = 0; m < 2; ++m)
#pragma unroll
      for (int ks = 0; ks < 4; ++ks)
        a[m][ks] = *(const int4v*)(sAb + aRow[m] + co[ks]);
#pragma unroll
    for (int ks = 0; ks < 4; ++ks)
      b0[ks] = *(const int4v*)(sBb + bRow[0] + co[ks]);
    STAGE_A(kk, 0, nb); STAGE_A(kk, 2, nb);
    __builtin_amdgcn_s_barrier();
    __builtin_amdgcn_s_setprio(1);
#pragma unroll
    for (int ks = 0; ks < 4; ++ks) {
      acc[0][0] = __builtin_amdgcn_mfma_i32_32x32x32_i8(a[0][ks], b0[ks], acc[0][0], 0, 0, 0);
      acc[1][0] = __builtin_amdgcn_mfma_i32_32x32x32_i8(a[1][ks], b0[ks], acc[1][0], 0, 0, 0);
    }
    __builtin_amdgcn_s_setprio(0);

    // -------- phase 1: reads B-n1 | stage B q0,q1 | vmcnt(4) | MFMA (m0,m1) x n1 --------
#pragma unroll
    for (int ks = 0; ks < 4; ++ks)
      b1[ks] = *(const int4v*)(sBb + bRow[1] + co[ks]);
    STAGE_B(kk, 0, nb); STAGE_B(kk, 1, nb);
    asm volatile("s_waitcnt vmcnt(4)" ::: "memory");  // retires S(t,Aq1),S(t,Aq3)
    __builtin_amdgcn_s_barrier();
    __builtin_amdgcn_s_setprio(1);
#pragma unroll
    for (int ks = 0; ks < 4; ++ks) {
      acc[0][1] = __builtin_amdgcn_mfma_i32_32x32x32_i8(a[0][ks], b1[ks], acc[0][1], 0, 0, 0);
      acc[1][1] = __builtin_amdgcn_mfma_i32_32x32x32_i8(a[1][ks], b1[ks], acc[1][1], 0, 0, 0);
    }
    __builtin_amdgcn_s_setprio(0);

    // -------- phase 2: reads A-mh1 | stage B q2,q3 | MFMA (m2,m3) x n1 --------
#pragma unroll
    for (int m = 0; m < 2; ++m)
#pragma unroll
      for (int ks = 0; ks < 4; ++ks)
        a[m][ks] = *(const int4v*)(sAb + aRow[2 + m] + co[ks]);
    STAGE_B(kk, 2, nb); STAGE_B(kk, 3, nb);
    __builtin_amdgcn_s_barrier();
    __builtin_amdgcn_s_setprio(1);
#pragma unroll
    for (int ks = 0; ks < 4; ++ks) {
      acc[2][1] = __builtin_amdgcn_mfma_i32_32x32x32_i8(a[0][ks], b1[ks], acc[2][1], 0, 0, 0);
      acc[3][1] = __builtin_amdgcn_mfma_i32_32x32x32_i8(a[1][ks], b1[ks], acc[3][1], 0, 0, 0);
    }
    __builtin_amdgcn_s_setprio(0);

    // -------- phase 3: stage A q1,q3 | vmcnt(2) | MFMA (m2,m3) x n0 --------
    STAGE_A(kk, 1, nb); STAGE_A(kk, 3, nb);
    asm volatile("s_waitcnt vmcnt(2)" ::: "memory");  // retires t+1's early-six
    __builtin_amdgcn_s_barrier();
    __builtin_amdgcn_s_setprio(1);
#pragma unroll
    for (int ks = 0; ks < 4; ++ks) {
      acc[2][0] = __builtin_amdgcn_mfma_i32_32x32x32_i8(a[0][ks], b0[ks], acc[2][0], 0, 0, 0);
      acc[3][0] = __builtin_amdgcn_mfma_i32_32x32x32_i8(a[1][ks], b0[ks], acc[3][0], 0, 0, 0);
    }
    __builtin_amdgcn_s_setprio(0);
  }
  asm volatile("s_waitcnt vmcnt(0)" ::: "memory");  // drain tail stages before epilogue

  // epilogue: 32x32 C/D layout col=lane&31, row=(reg&3)+8*(reg>>2)+4*(lane>>5)
  const float s = ws_ptr[0] * xs_ptr[0];
#pragma unroll
  for (int m = 0; m < 4; ++m) {
#pragma unroll
    for (int n = 0; n < 2; ++n) {
      const long col = n0 + wc * 64 + n * 32 + r;
      const long rowbase = m0 + wr * 128 + m * 32 + 4 * half;
#pragma unroll
      for (int reg = 0; reg < 16; ++reg) {
        const long row = rowbase + (reg & 3) + 8 * (reg >> 2);
        C[row * N_DIM + col] = (float)acc[m][n][reg] * s;
      }
    }
  }
#undef STAGE_A
#undef STAGE_B
}

extern "C" void kernel_launch(void* const* d_in, const int* in_sizes, int n_in,
                              void* d_out, int out_size, void* d_ws, size_t ws_size,
                              hipStream_t stream) {
  const float* x  = (const float*)d_in[0];   // [8192,4096]
  const float* w  = (const float*)d_in[1];   // [4096,4096]
  const float* ws = (const float*)d_in[2];   // [1]
  const float* xs = (const float*)d_in[3];   // [1]
  float* out = (float*)d_out;

  int8_t* xq = (int8_t*)d_ws;
  int8_t* wq = (int8_t*)d_ws + (size_t)M_DIM * K_DIM;

  const int nx_blocks = (int)((long)M_DIM * K_DIM / 2048);   // 16384
  const int nw_blocks = (int)((long)N_DIM * K_DIM / 2048);   // 8192
  quant_fused<<<nx_blocks + nw_blocks, 256, 0, stream>>>(x, xq, w, wq, xs, ws, nx_blocks);

  dim3 grid(N_DIM / BN, M_DIM / BM);   // 16 x 32 = 512 blocks, 2 passes over 256 CUs
  gemm_bt<<<grid, 512, 0, stream>>>(xq, wq, out, ws, xs);
}

// Round 4
// 386.036 us; speedup vs baseline: 1.0644x; 1.0435x over previous
//
#include <hip/hip_runtime.h>
#include <stdint.h>

// BitLinear: out[t,o] = (sum_i clip(rint(x/xs)) * clip(rint(w/ws))) * xs*ws
// M=8192, N=4096, K=4096.
// R5 (resubmit; R3 bench was an infra failure, no signal): merge 4 phases -> 2
// phases per K-tile (16-MFMA bursts, 2 barriers/tile).
// Rationale (R2 counters): 5625 cy/tile measured vs MFMA 2345 + LDS 2048 serialized;
// the 12.58M bank-conflict cycles are the inherent 2nd cycle of b128 quarter-groups
// (192 reads x 4 groups = 768/tile exactly), not fixable. The gap is lockstep
// serialization -> fewer/longer phases.
//   phase A: reads {Aq0,Aq2,B q0-q3} of tile t | stage 6 {t+1: Aq0,Aq2,Bq0..3}
//            | vmcnt(6) | barrier | 16 MFMA (m0,m1 x n0,n1)
//   phase B: reads {Aq1,Aq3}          | stage 2 {t+1: Aq1,Aq3}
//            | lgkmcnt(0) (reads must land before next phA's DMA clobbers buf)
//            | vmcnt(2) | barrier | 16 MFMA (m2,m3 x n0,n1)
// Ledger (1 wave-instr per stage): enter phA with 2 in flight {t:Aq1,Aq3};
// phA +6 -> 8, vmcnt(6) retires {t:Aq1,Aq3} (phB reads them);
// phB +2 -> 8, vmcnt(2) retires {t+1: Aq0,Aq2,Bq0..3} (next phA reads them).
// Every stage has >= 1 full phase of latency slack; never vmcnt(0) in the loop.

typedef int  int4v  __attribute__((ext_vector_type(4)));
typedef int  int16v __attribute__((ext_vector_type(16)));

typedef __attribute__((address_space(1))) void gvoid;
typedef __attribute__((address_space(3))) void lvoid;

#define M_DIM 8192
#define N_DIM 4096
#define K_DIM 4096

#define BM 256
#define BN 256
#define BK 128          // K-bytes per tile
#define NT (K_DIM / BK) // 32 K-tiles

// ---------------- quantize: fp32 -> int8 (fused, fully coalesced) ----------------
__global__ __launch_bounds__(256) void quant_fused(
    const float* __restrict__ x, int8_t* __restrict__ xq,
    const float* __restrict__ w, int8_t* __restrict__ wq,
    const float* __restrict__ xs_ptr, const float* __restrict__ ws_ptr,
    int nx_blocks) {
  const bool isX = ((int)blockIdx.x < nx_blocks);
  const float* __restrict__ in  = isX ? x : w;
  int8_t* __restrict__ out      = isX ? xq : wq;
  const float s  = isX ? xs_ptr[0] : ws_ptr[0];
  const float lo = isX ? -128.f : -1.f;
  const float hi = isX ?  127.f :  1.f;
  const long base = (long)(isX ? blockIdx.x : (blockIdx.x - nx_blocks)) * 2048;
#pragma unroll
  for (int p = 0; p < 2; ++p) {
    const long i = base + (long)p * 1024 + (long)threadIdx.x * 4;
    float4 v = *(const float4*)(in + i);
    float e[4] = {v.x, v.y, v.z, v.w};
    union { int8_t c[4]; int u; } u;
#pragma unroll
    for (int t = 0; t < 4; ++t) {
      float q = rintf(e[t] / s);          // round-half-even, matches np.round
      q = fminf(fmaxf(q, lo), hi);
      u.c[t] = (int8_t)q;
    }
    *(int*)(out + i) = u.u;
  }
}

// ---------------- GEMM: C[M,N] = A[M,K] * B[N,K]^T (i8 -> i32), scaled ----------------
__global__ __launch_bounds__(512, 2) void gemm_bt(
    const int8_t* __restrict__ A,   // [M,K] i8 (x_q)
    const int8_t* __restrict__ B,   // [N,K] i8 (w_q)
    float* __restrict__ C,          // [M,N]
    const float* __restrict__ ws_ptr, const float* __restrict__ xs_ptr) {
  // LDS: A buffers [2][256][128] at 0; B buffers [2][256][128] at 65536.
  __shared__ __attribute__((aligned(16))) char smem[131072];

  const int tid  = threadIdx.x;
  const int wid  = tid >> 6;      // 0..7
  const int lane = tid & 63;
  const int wr   = wid >> 2;      // 0..1 -> 128-row strip of C
  const int wc   = wid & 3;       // 0..3 -> 64-col strip of C
  const int r    = lane & 31;     // MFMA row/col within 32-tile
  const int half = lane >> 5;     // k-half of fragment

  // XCD swizzle: 512 blocks, 8 XCDs; column-grouped, bijective (512 % 8 == 0).
  const int fl  = blockIdx.y * gridDim.x + blockIdx.x;   // 0..511, x-fastest HW order
  const int vid = (fl & 7) * 64 + (fl >> 3);
  const long m0 = (long)(vid & 31) * BM;
  const long n0 = (long)(vid >> 5) * BN;

  // ---- staging addressing ----
  // One stage call = 512 threads x 16B = 8 KB = 64 rows ("quarter").
  // LDS dest linear (base + lane*16); source chunk pre-swizzled: (lane&7)^(row&7).
  const int srow   = wid * 8 + (lane >> 3);
  const int schunk = ((lane & 7) ^ (lane >> 3)) * 16;
  const int8_t* gA = A + (m0 + srow) * K_DIM + schunk;
  const int8_t* gB = B + (n0 + srow) * K_DIM + schunk;
  const int ldst = wid * 1024;   // wave's LDS offset within a quarter (HW adds lane*16)

  // ---- fragment read offsets (bytes) ----
  // frag (row, kstep ks): byte = row*128 + (((ks*2+half) ^ (row&7)) * 16); row&7 == r&7.
  int aRow[4], bRow[2], co[4];
#pragma unroll
  for (int m = 0; m < 4; ++m) aRow[m] = (wr * 128 + m * 32 + r) * BK;
#pragma unroll
  for (int n = 0; n < 2; ++n) bRow[n] = (wc * 64 + n * 32 + r) * BK;
#pragma unroll
  for (int ks = 0; ks < 4; ++ks) co[ks] = ((ks * 2 + half) ^ (r & 7)) * 16;

#define STAGE_A(kk, q, nb)                                                         \
  __builtin_amdgcn_global_load_lds(                                                \
      (gvoid*)(gA + (long)(kk) * BK + (long)(q) * 64 * K_DIM),                     \
      (lvoid*)(smem + (nb) * 32768 + (q) * 8192 + ldst), 16, 0, 0)
#define STAGE_B(kk, q, nb)                                                         \
  __builtin_amdgcn_global_load_lds(                                                \
      (gvoid*)(gB + (long)(kk) * BK + (long)(q) * 64 * K_DIM),                     \
      (lvoid*)(smem + 65536 + (nb) * 32768 + (q) * 8192 + ldst), 16, 0, 0)

  // ---- prologue: tile 0 -> buf 0. Order: early-six {Aq0,Aq2,Bq0..3}, late-two {Aq1,Aq3}.
  STAGE_A(0, 0, 0); STAGE_A(0, 2, 0);
  STAGE_B(0, 0, 0); STAGE_B(0, 1, 0); STAGE_B(0, 2, 0); STAGE_B(0, 3, 0);
  STAGE_A(0, 1, 0); STAGE_A(0, 3, 0);
  asm volatile("s_waitcnt vmcnt(2)" ::: "memory");  // early-six landed; 2 in flight
  __builtin_amdgcn_s_barrier();

  int4v  a[2][4], b0[4], b1[4];
  int16v acc[4][2] = {};

#pragma unroll 2
  for (int t = 0; t < NT; ++t) {
    const int bi = t & 1;
    const int nb = bi ^ 1;
    const char* sAb = smem + bi * 32768;
    const char* sBb = smem + 65536 + bi * 32768;
    int kk = t + 1; if (kk >= NT) kk = NT - 1;  // last iter re-stages tile 31 (unread, in-bounds)

    // ======== phase A: reads {A-mh0 (Aq0,Aq2), B n0+n1 (Bq0..3)} | stage 6 | MFMA 16 ========
#pragma unroll
    for (int m = 0; m < 2; ++m)
#pragma unroll
      for (int ks = 0; ks < 4; ++ks)
        a[m][ks] = *(const int4v*)(sAb + aRow[m] + co[ks]);
#pragma unroll
    for (int ks = 0; ks < 4; ++ks)
      b0[ks] = *(const int4v*)(sBb + bRow[0] + co[ks]);
#pragma unroll
    for (int ks = 0; ks < 4; ++ks)
      b1[ks] = *(const int4v*)(sBb + bRow[1] + co[ks]);
    STAGE_A(kk, 0, nb); STAGE_A(kk, 2, nb);
    STAGE_B(kk, 0, nb); STAGE_B(kk, 1, nb); STAGE_B(kk, 2, nb); STAGE_B(kk, 3, nb);
    asm volatile("s_waitcnt vmcnt(6)" ::: "memory");  // retires {t:Aq1,Aq3} for phase B reads
    __builtin_amdgcn_s_barrier();
    __builtin_amdgcn_s_setprio(1);
#pragma unroll
    for (int ks = 0; ks < 4; ++ks) {
      acc[0][0] = __builtin_amdgcn_mfma_i32_32x32x32_i8(a[0][ks], b0[ks], acc[0][0], 0, 0, 0);
      acc[1][0] = __builtin_amdgcn_mfma_i32_32x32x32_i8(a[1][ks], b0[ks], acc[1][0], 0, 0, 0);
      acc[0][1] = __builtin_amdgcn_mfma_i32_32x32x32_i8(a[0][ks], b1[ks], acc[0][1], 0, 0, 0);
      acc[1][1] = __builtin_amdgcn_mfma_i32_32x32x32_i8(a[1][ks], b1[ks], acc[1][1], 0, 0, 0);
    }
    __builtin_amdgcn_s_setprio(0);

    // ======== phase B: reads {A-mh1 (Aq1,Aq3)} | stage 2 | lgkm fence | MFMA 16 ========
#pragma unroll
    for (int m = 0; m < 2; ++m)
#pragma unroll
      for (int ks = 0; ks < 4; ++ks)
        a[m][ks] = *(const int4v*)(sAb + aRow[2 + m] + co[ks]);
    STAGE_A(kk, 1, nb); STAGE_A(kk, 3, nb);
    // phase-B reads are consumed AFTER the barrier; next phase-A's DMA writes hit the
    // buffer they read. Force them into registers before the barrier.
    asm volatile("s_waitcnt lgkmcnt(0)" ::: "memory");
    asm volatile("s_waitcnt vmcnt(2)" ::: "memory");  // retires {t+1: Aq0,Aq2,Bq0..3}
    __builtin_amdgcn_s_barrier();
    __builtin_amdgcn_s_setprio(1);
#pragma unroll
    for (int ks = 0; ks < 4; ++ks) {
      acc[2][0] = __builtin_amdgcn_mfma_i32_32x32x32_i8(a[0][ks], b0[ks], acc[2][0], 0, 0, 0);
      acc[3][0] = __builtin_amdgcn_mfma_i32_32x32x32_i8(a[1][ks], b0[ks], acc[3][0], 0, 0, 0);
      acc[2][1] = __builtin_amdgcn_mfma_i32_32x32x32_i8(a[0][ks], b1[ks], acc[2][1], 0, 0, 0);
      acc[3][1] = __builtin_amdgcn_mfma_i32_32x32x32_i8(a[1][ks], b1[ks], acc[3][1], 0, 0, 0);
    }
    __builtin_amdgcn_s_setprio(0);
  }
  asm volatile("s_waitcnt vmcnt(0)" ::: "memory");  // drain tail stages before epilogue

  // epilogue: 32x32 C/D layout col=lane&31, row=(reg&3)+8*(reg>>2)+4*(lane>>5)
  const float s = ws_ptr[0] * xs_ptr[0];
#pragma unroll
  for (int m = 0; m < 4; ++m) {
#pragma unroll
    for (int n = 0; n < 2; ++n) {
      const long col = n0 + wc * 64 + n * 32 + r;
      const long rowbase = m0 + wr * 128 + m * 32 + 4 * half;
#pragma unroll
      for (int reg = 0; reg < 16; ++reg) {
        const long row = rowbase + (reg & 3) + 8 * (reg >> 2);
        C[row * N_DIM + col] = (float)acc[m][n][reg] * s;
      }
    }
  }
#undef STAGE_A
#undef STAGE_B
}

extern "C" void kernel_launch(void* const* d_in, const int* in_sizes, int n_in,
                              void* d_out, int out_size, void* d_ws, size_t ws_size,
                              hipStream_t stream) {
  const float* x  = (const float*)d_in[0];   // [8192,4096]
  const float* w  = (const float*)d_in[1];   // [4096,4096]
  const float* ws = (const float*)d_in[2];   // [1]
  const float* xs = (const float*)d_in[3];   // [1]
  float* out = (float*)d_out;

  int8_t* xq = (int8_t*)d_ws;
  int8_t* wq = (int8_t*)d_ws + (size_t)M_DIM * K_DIM;

  const int nx_blocks = (int)((long)M_DIM * K_DIM / 2048);   // 16384
  const int nw_blocks = (int)((long)N_DIM * K_DIM / 2048);   // 8192
  quant_fused<<<nx_blocks + nw_blocks, 256, 0, stream>>>(x, xq, w, wq, xs, ws, nx_blocks);

  dim3 grid(N_DIM / BN, M_DIM / BM);   // 16 x 32 = 512 blocks, 2 passes over 256 CUs
  gemm_bt<<<grid, 512, 0, stream>>>(xq, wq, out, ws, xs);
}

// Round 5
// 383.905 us; speedup vs baseline: 1.0703x; 1.0056x over previous
//
#include <hip/hip_runtime.h>
#include <stdint.h>

// BitLinear: out[t,o] = (sum_i clip(rint(x/xs)) * clip(rint(w/ws))) * xs*ws
// M=8192, N=4096, K=4096.
// R6: quarter-granularity software pipeline with dual register fragment sets.
// R4 post-mortem: phases serialized CU-wide (reads 1536+768 cy with MFMA idle,
// MFMA 2x1171 cy with LDS idle, +sync = 5365 cy/tile). Fix: interleave reads of
// k-quarter q+1 (into fragment set F_alt) under the 8-MFMA burst of quarter q
// (consuming F_cur) -- a wave stalls ~36cy per MFMA issue; ds_reads issue in
// those windows. One sync cluster per tile, placed before Q3:
//   Q0: MFMA(F0=t,q0) || read(t,q1)->F1          [buf bi]
//   Q1: MFMA(F1)      || read(t,q2)->F0
//   Q2: MFMA(F0)      || read(t,q3)->F1
//   lgkm(0); barrier   // all waves' reads of buf[bi] landed
//   S8(t+2 -> buf[bi]) // safe overwrite of current buffer
//   vmcnt(8)           // retire t+1's 8 stages (staged last tile, ~1 tile slack)
//   barrier            // publish t+1
//   Q3: MFMA(F1)      || read(t+1,q0)->F0        [buf bi^1]
// Ledger: in-flight 8 -> 16 -> 8 per tile; vmcnt never 0 in the loop.
// Fragment regs drop 64->48 (two 24-reg sets), keeping total <= 256/wave.

typedef int  int4v  __attribute__((ext_vector_type(4)));
typedef int  int16v __attribute__((ext_vector_type(16)));

typedef __attribute__((address_space(1))) void gvoid;
typedef __attribute__((address_space(3))) void lvoid;

#define M_DIM 8192
#define N_DIM 4096
#define K_DIM 4096

#define BM 256
#define BN 256
#define BK 128          // K-bytes per tile
#define NT (K_DIM / BK) // 32 K-tiles

// ---------------- quantize: fp32 -> int8 (fused, fully coalesced) ----------------
__global__ __launch_bounds__(256) void quant_fused(
    const float* __restrict__ x, int8_t* __restrict__ xq,
    const float* __restrict__ w, int8_t* __restrict__ wq,
    const float* __restrict__ xs_ptr, const float* __restrict__ ws_ptr,
    int nx_blocks) {
  const bool isX = ((int)blockIdx.x < nx_blocks);
  const float* __restrict__ in  = isX ? x : w;
  int8_t* __restrict__ out      = isX ? xq : wq;
  const float s  = isX ? xs_ptr[0] : ws_ptr[0];
  const float lo = isX ? -128.f : -1.f;
  const float hi = isX ?  127.f :  1.f;
  const long base = (long)(isX ? blockIdx.x : (blockIdx.x - nx_blocks)) * 2048;
#pragma unroll
  for (int p = 0; p < 2; ++p) {
    const long i = base + (long)p * 1024 + (long)threadIdx.x * 4;
    float4 v = *(const float4*)(in + i);
    float e[4] = {v.x, v.y, v.z, v.w};
    union { int8_t c[4]; int u; } u;
#pragma unroll
    for (int t = 0; t < 4; ++t) {
      float q = rintf(e[t] / s);          // round-half-even, matches np.round
      q = fminf(fmaxf(q, lo), hi);
      u.c[t] = (int8_t)q;
    }
    *(int*)(out + i) = u.u;
  }
}

// ---------------- GEMM: C[M,N] = A[M,K] * B[N,K]^T (i8 -> i32), scaled ----------------
__global__ __launch_bounds__(512, 2) void gemm_bt(
    const int8_t* __restrict__ A,   // [M,K] i8 (x_q)
    const int8_t* __restrict__ B,   // [N,K] i8 (w_q)
    float* __restrict__ C,          // [M,N]
    const float* __restrict__ ws_ptr, const float* __restrict__ xs_ptr) {
  // LDS: A buffers [2][256][128] at 0; B buffers [2][256][128] at 65536.
  __shared__ __attribute__((aligned(16))) char smem[131072];

  const int tid  = threadIdx.x;
  const int wid  = tid >> 6;      // 0..7
  const int lane = tid & 63;
  const int wr   = wid >> 2;      // 0..1 -> 128-row strip of C
  const int wc   = wid & 3;       // 0..3 -> 64-col strip of C
  const int r    = lane & 31;     // MFMA row/col within 32-tile
  const int half = lane >> 5;     // k-half of fragment

  // XCD swizzle: 512 blocks, 8 XCDs; column-grouped, bijective (512 % 8 == 0).
  const int fl  = blockIdx.y * gridDim.x + blockIdx.x;   // 0..511, x-fastest HW order
  const int vid = (fl & 7) * 64 + (fl >> 3);
  const long m0 = (long)(vid & 31) * BM;
  const long n0 = (long)(vid >> 5) * BN;

  // ---- staging addressing ----
  // One stage call = 512 threads x 16B = 8 KB = 64 rows ("quarter").
  // LDS dest linear (base + lane*16); source chunk pre-swizzled: (lane&7)^(row&7).
  const int srow   = wid * 8 + (lane >> 3);
  const int schunk = ((lane & 7) ^ (lane >> 3)) * 16;
  const int8_t* gA = A + (m0 + srow) * K_DIM + schunk;
  const int8_t* gB = B + (n0 + srow) * K_DIM + schunk;
  const int ldst = wid * 1024;   // wave's LDS offset within a quarter (HW adds lane*16)

  // ---- fragment read offsets (bytes) ----
  // frag (row, k-quarter q): byte = row*128 + (((q*2+half) ^ (row&7)) * 16); row&7 == r&7.
  int aRow[4], bRow[2], co[4];
#pragma unroll
  for (int m = 0; m < 4; ++m) aRow[m] = (wr * 128 + m * 32 + r) * BK;
#pragma unroll
  for (int n = 0; n < 2; ++n) bRow[n] = (wc * 64 + n * 32 + r) * BK;
#pragma unroll
  for (int q = 0; q < 4; ++q) co[q] = ((q * 2 + half) ^ (r & 7)) * 16;

#define STAGE_A(kk, q, nb)                                                         \
  __builtin_amdgcn_global_load_lds(                                                \
      (gvoid*)(gA + (long)(kk) * BK + (long)(q) * 64 * K_DIM),                     \
      (lvoid*)(smem + (nb) * 32768 + (q) * 8192 + ldst), 16, 0, 0)
#define STAGE_B(kk, q, nb)                                                         \
  __builtin_amdgcn_global_load_lds(                                                \
      (gvoid*)(gB + (long)(kk) * BK + (long)(q) * 64 * K_DIM),                     \
      (lvoid*)(smem + 65536 + (nb) * 32768 + (q) * 8192 + ldst), 16, 0, 0)
#define STAGE8(kk, nb)                                                             \
  do {                                                                             \
    STAGE_A(kk, 0, nb); STAGE_A(kk, 1, nb); STAGE_A(kk, 2, nb); STAGE_A(kk, 3, nb);\
    STAGE_B(kk, 0, nb); STAGE_B(kk, 1, nb); STAGE_B(kk, 2, nb); STAGE_B(kk, 3, nb);\
  } while (0)

  // MFMA burst of one quarter (consumes FMa/FMb) interleaved with the 6 reads of the
  // next quarter (writes RDa/RDb, disjoint regs -> no deps; scheduler fills MFMA
  // issue-stall windows with ds_read issues).
#define QSTEP(FMa, FMb, RDa, RDb, rsA, rsB, q)                                     \
  do {                                                                             \
    RDa[0] = *(const int4v*)((rsA) + aRow[0] + co[q]);                             \
    acc[0][0] = __builtin_amdgcn_mfma_i32_32x32x32_i8(FMa[0], FMb[0], acc[0][0], 0, 0, 0); \
    RDa[1] = *(const int4v*)((rsA) + aRow[1] + co[q]);                             \
    acc[0][1] = __builtin_amdgcn_mfma_i32_32x32x32_i8(FMa[0], FMb[1], acc[0][1], 0, 0, 0); \
    RDa[2] = *(const int4v*)((rsA) + aRow[2] + co[q]);                             \
    acc[1][0] = __builtin_amdgcn_mfma_i32_32x32x32_i8(FMa[1], FMb[0], acc[1][0], 0, 0, 0); \
    RDa[3] = *(const int4v*)((rsA) + aRow[3] + co[q]);                             \
    acc[1][1] = __builtin_amdgcn_mfma_i32_32x32x32_i8(FMa[1], FMb[1], acc[1][1], 0, 0, 0); \
    RDb[0] = *(const int4v*)((rsB) + bRow[0] + co[q]);                             \
    acc[2][0] = __builtin_amdgcn_mfma_i32_32x32x32_i8(FMa[2], FMb[0], acc[2][0], 0, 0, 0); \
    RDb[1] = *(const int4v*)((rsB) + bRow[1] + co[q]);                             \
    acc[2][1] = __builtin_amdgcn_mfma_i32_32x32x32_i8(FMa[2], FMb[1], acc[2][1], 0, 0, 0); \
    acc[3][0] = __builtin_amdgcn_mfma_i32_32x32x32_i8(FMa[3], FMb[0], acc[3][0], 0, 0, 0); \
    acc[3][1] = __builtin_amdgcn_mfma_i32_32x32x32_i8(FMa[3], FMb[1], acc[3][1], 0, 0, 0); \
  } while (0)

  // ---- prologue: stage tiles 0,1; publish tile 0; read (t0,q0) into F0 ----
  STAGE8(0, 0);                                      // 8 in flight
  STAGE8(1, 1);                                      // 16 in flight
  asm volatile("s_waitcnt vmcnt(8)" ::: "memory");   // tile 0 retired (mine)
  __builtin_amdgcn_s_barrier();                      // tile 0 published
  int4v fa0[4], fb0[2], fa1[4], fb1[2];
  {
    const char* sA0 = smem;
    const char* sB0 = smem + 65536;
#pragma unroll
    for (int m = 0; m < 4; ++m) fa0[m] = *(const int4v*)(sA0 + aRow[m] + co[0]);
#pragma unroll
    for (int n = 0; n < 2; ++n) fb0[n] = *(const int4v*)(sB0 + bRow[n] + co[0]);
  }

  int16v acc[4][2] = {};

#pragma unroll 2
  for (int t = 0; t < NT; ++t) {
    const int bi = t & 1;
    const char* sA0 = smem + bi * 32768;               // tile t
    const char* sB0 = smem + 65536 + bi * 32768;
    const char* sA1 = smem + (bi ^ 1) * 32768;         // tile t+1
    const char* sB1 = smem + 65536 + (bi ^ 1) * 32768;
    int kk = t + 2; if (kk >= NT) kk = NT - 1;  // tail re-stages tile 31 (unread, in-bounds)

    // Q0: MFMA(t,q0)=F0 || read (t,q1)->F1
    QSTEP(fa0, fb0, fa1, fb1, sA0, sB0, 1);
    // Q1: MFMA(t,q1)=F1 || read (t,q2)->F0
    QSTEP(fa1, fb1, fa0, fb0, sA0, sB0, 2);
    // Q2: MFMA(t,q2)=F0 || read (t,q3)->F1
    QSTEP(fa0, fb0, fa1, fb1, sA0, sB0, 3);

    // sync cluster: protect buf[bi] overwrite, publish tile t+1
    asm volatile("s_waitcnt lgkmcnt(0)" ::: "memory");  // all my reads of buf[bi] landed
    __builtin_amdgcn_s_barrier();                       // ... for all waves
    STAGE8(kk, bi);                                     // in-flight 8 -> 16
    asm volatile("s_waitcnt vmcnt(8)" ::: "memory");    // retire t+1's stages (1-tile slack)
    __builtin_amdgcn_s_barrier();                       // publish tile t+1

    // Q3: MFMA(t,q3)=F1 || read (t+1,q0)->F0 from the other buffer
    QSTEP(fa1, fb1, fa0, fb0, sA1, sB1, 0);
  }
  asm volatile("s_waitcnt vmcnt(0)" ::: "memory");  // drain tail stages before epilogue

  // epilogue: 32x32 C/D layout col=lane&31, row=(reg&3)+8*(reg>>2)+4*(lane>>5)
  const float s = ws_ptr[0] * xs_ptr[0];
#pragma unroll
  for (int m = 0; m < 4; ++m) {
#pragma unroll
    for (int n = 0; n < 2; ++n) {
      const long col = n0 + wc * 64 + n * 32 + r;
      const long rowbase = m0 + wr * 128 + m * 32 + 4 * half;
#pragma unroll
      for (int reg = 0; reg < 16; ++reg) {
        const long row = rowbase + (reg & 3) + 8 * (reg >> 2);
        C[row * N_DIM + col] = (float)acc[m][n][reg] * s;
      }
    }
  }
#undef STAGE_A
#undef STAGE_B
#undef STAGE8
#undef QSTEP
}

extern "C" void kernel_launch(void* const* d_in, const int* in_sizes, int n_in,
                              void* d_out, int out_size, void* d_ws, size_t ws_size,
                              hipStream_t stream) {
  const float* x  = (const float*)d_in[0];   // [8192,4096]
  const float* w  = (const float*)d_in[1];   // [4096,4096]
  const float* ws = (const float*)d_in[2];   // [1]
  const float* xs = (const float*)d_in[3];   // [1]
  float* out = (float*)d_out;

  int8_t* xq = (int8_t*)d_ws;
  int8_t* wq = (int8_t*)d_ws + (size_t)M_DIM * K_DIM;

  const int nx_blocks = (int)((long)M_DIM * K_DIM / 2048);   // 16384
  const int nw_blocks = (int)((long)N_DIM * K_DIM / 2048);   // 8192
  quant_fused<<<nx_blocks + nw_blocks, 256, 0, stream>>>(x, xq, w, wq, xs, ws, nx_blocks);

  dim3 grid(N_DIM / BN, M_DIM / BM);   // 16 x 32 = 512 blocks, 2 passes over 256 CUs
  gemm_bt<<<grid, 512, 0, stream>>>(xq, wq, out, ws, xs);
}